// Round 1
// baseline (940.436 us; speedup 1.0000x reference)
//
#include <hip/hip_runtime.h>

// ---------------------------------------------------------------------------
// CustomizedMultiHeadAttention: B=4 S=2048 D=1024 H=16 DH=64
// Outputs: out [B,S,D] f32, attn_weights [B,H,S,S] f32 (concat in d_out).
// Pipeline: cast/transpose -> 3x bf16 GEMM (QKV proj) -> 2-pass attention
//           (writes attn f32 + ctx bf16) -> output GEMM (f32 + bias).
// ---------------------------------------------------------------------------

typedef unsigned short u16;
typedef unsigned int   u32;
typedef u16   u16x4  __attribute__((ext_vector_type(4)));
typedef u16   u16x8  __attribute__((ext_vector_type(8)));
typedef int   i32x4  __attribute__((ext_vector_type(4)));
typedef float f32x4  __attribute__((ext_vector_type(4)));
typedef __bf16 bf16x8 __attribute__((ext_vector_type(8)));

#define GLDS16(gp, lp)                                                         \
  __builtin_amdgcn_global_load_lds(                                            \
      (const __attribute__((address_space(1))) void*)(gp),                     \
      (__attribute__((address_space(3))) void*)(lp), 16, 0, 0)

__device__ __forceinline__ u16 f2bf(float x) {
  union { float f; u32 u; } v; v.f = x;
  u32 r = v.u + 0x7FFFu + ((v.u >> 16) & 1u);   // RNE
  return (u16)(r >> 16);
}
__device__ __forceinline__ float bf2f(u16 x) {
  union { u32 u; float f; } v; v.u = ((u32)x) << 16; return v.f;
}

static const int  Bn = 4, Sn = 2048, Dn = 1024, Hn = 16, DHn = 64;

// ---------------------------------------------------------------- cast f32->bf16
__global__ __launch_bounds__(256) void cast_k(const float* __restrict__ in,
                                              u16* __restrict__ out) {
  size_t i = (size_t)blockIdx.x * 256 + threadIdx.x;   // 8 elems/thread
  const f32x4* p = (const f32x4*)in + i * 2;
  f32x4 a = p[0], b = p[1];
  u16x8 r;
  r[0]=f2bf(a[0]); r[1]=f2bf(a[1]); r[2]=f2bf(a[2]); r[3]=f2bf(a[3]);
  r[4]=f2bf(b[0]); r[5]=f2bf(b[1]); r[6]=f2bf(b[2]); r[7]=f2bf(b[3]);
  *((u16x8*)out + i) = r;
}

// ------------------------------------------- weight cast+transpose: WT[n][k]=W[k][n]
__global__ __launch_bounds__(256) void castWT_k(const float* __restrict__ W,
                                                u16* __restrict__ WT) {
  __shared__ u16 tile[64][72];
  int bx = blockIdx.x;  // n tile
  int by = blockIdx.y;  // k tile
  int t = threadIdx.x;
  for (int rr = 0; rr < 4; rr++) {
    int r = rr * 16 + (t >> 4);     // k-local
    int c = (t & 15) * 4;           // n-local
    float4 v = *(const float4*)(W + (size_t)(by * 64 + r) * 1024 + bx * 64 + c);
    tile[c + 0][r] = f2bf(v.x); tile[c + 1][r] = f2bf(v.y);
    tile[c + 2][r] = f2bf(v.z); tile[c + 3][r] = f2bf(v.w);
  }
  __syncthreads();
  for (int rr = 0; rr < 2; rr++) {
    int gid = rr * 256 + t;
    int r = gid >> 3, g = gid & 7;  // r = n-local
    u16x8 v = *(const u16x8*)&tile[r][g * 8];
    *(u16x8*)(WT + (size_t)(bx * 64 + r) * 1024 + by * 64 + g * 8) = v;
  }
}

// ------------------------------------------------- mask transpose: MT[b][sk][sq]
__global__ __launch_bounds__(256) void maskT_k(const float* __restrict__ M,
                                               float* __restrict__ MT) {
  __shared__ float tile[64][65];
  int bx = blockIdx.x;  // sk tile
  int by = blockIdx.y;  // sq tile
  int b  = blockIdx.z;
  int t = threadIdx.x;
  const float* src = M + (size_t)b * Sn * Sn;
  for (int rr = 0; rr < 4; rr++) {
    int r = rr * 16 + (t >> 4);  // sq-local
    int c = (t & 15) * 4;        // sk-local
    float4 v = *(const float4*)(src + (size_t)(by * 64 + r) * Sn + bx * 64 + c);
    tile[r][c] = v.x; tile[r][c + 1] = v.y; tile[r][c + 2] = v.z; tile[r][c + 3] = v.w;
  }
  __syncthreads();
  float* dst = MT + (size_t)b * Sn * Sn;
  for (int rr = 0; rr < 4; rr++) {
    int r = rr * 16 + (t >> 4);  // sk-local
    int c = (t & 15) * 4;        // sq-local
    float4 o;
    o.x = tile[c][r]; o.y = tile[c + 1][r]; o.z = tile[c + 2][r]; o.w = tile[c + 3][r];
    *(float4*)(dst + (size_t)(bx * 64 + r) * Sn + by * 64 + c) = o;
  }
}

// --------------------------------- all-ones flags per [64 sk x 128 sq] mask tile
__global__ __launch_bounds__(256) void flags_k(const float* __restrict__ MT,
                                               int* __restrict__ flags) {
  __shared__ int ok_s;
  int t = threadIdx.x;
  if (t == 0) ok_s = 1;
  __syncthreads();
  int qt = blockIdx.x, kt = blockIdx.y, b = blockIdx.z;
  const float* base = MT + ((size_t)b * Sn + kt * 64) * Sn + qt * 128;
  int r = t >> 2, c0 = (t & 3) * 32;
  const float* p = base + (size_t)r * Sn + c0;
  bool ok = true;
  for (int i = 0; i < 8; i++) {
    float4 v = *(const float4*)(p + i * 4);
    ok = ok && (v.x == 1.0f) && (v.y == 1.0f) && (v.z == 1.0f) && (v.w == 1.0f);
  }
  if (!ok) atomicAnd(&ok_s, 0);
  __syncthreads();
  if (t == 0) flags[(b * 32 + kt) * 16 + qt] = ok_s;
}

// ---------------------------------------------------------------------------
// GEMM: C[8192x1024] = A[8192x1024](bf16) @ BT[1024x1024](bf16, B^T) + bias
// 128x128 tile, BK=64, 4 waves, global_load_lds w=16, XOR-swizzled LDS
// (linear dest + pre-swizzled global source; read applies same XOR).
// mode 0: Q head-split bf16, *0.125 ; mode 1: K head-split bf16
// mode 2: V -> vt[b][h][d][s] bf16  ; mode 3: f32 flat out (+bias)
// ---------------------------------------------------------------------------
__global__ __launch_bounds__(256) void gemm_k(const u16* __restrict__ A,
                                              const u16* __restrict__ BT,
                                              const float* __restrict__ bias,
                                              void* __restrict__ outp, int mode) {
  __shared__ __align__(16) char sm[32768];   // A 16KB @0, B 16KB @16384
  const int K = 1024;
  int nt = blockIdx.x, mt = blockIdx.y;
  int m0 = mt * 128, n0 = nt * 128;
  int tid = threadIdx.x, w = tid >> 6, l = tid & 63, l15 = l & 15, l4 = l >> 4;
  int wm = w >> 1, wn = w & 1;

  size_t goff_a[4], goff_b[4];
  int lbase[4];
  for (int i = 0; i < 4; i++) {
    int gi = (w * 4 + i) * 64 + l;       // granule 0..1023
    int row = gi >> 3, g = gi & 7;
    int gx = g ^ (row & 7);              // inverse-swizzled source granule
    goff_a[i] = (size_t)(m0 + row) * K + gx * 8;
    goff_b[i] = (size_t)(n0 + row) * K + gx * 8;
    lbase[i] = (w * 4 + i) * 1024;
  }

  f32x4 acc[4][4] = {};
  for (int t = 0; t < 16; t++) {
    int k0 = t * 64;
    for (int i = 0; i < 4; i++) {
      GLDS16(A + goff_a[i] + k0, sm + lbase[i]);
      GLDS16(BT + goff_b[i] + k0, sm + 16384 + lbase[i]);
    }
    __syncthreads();
#pragma unroll
    for (int kk = 0; kk < 2; kk++) {
      int kb = kk * 64 + l4 * 16;
      bf16x8 af[4], bf[4];
#pragma unroll
      for (int mi = 0; mi < 4; mi++) {
        int row = wm * 64 + mi * 16 + l15;
        af[mi] = *(const bf16x8*)(sm + row * 128 + (kb ^ ((row & 7) << 4)));
      }
#pragma unroll
      for (int nj = 0; nj < 4; nj++) {
        int row = wn * 64 + nj * 16 + l15;
        bf[nj] = *(const bf16x8*)(sm + 16384 + row * 128 + (kb ^ ((row & 7) << 4)));
      }
#pragma unroll
      for (int mi = 0; mi < 4; mi++)
#pragma unroll
        for (int nj = 0; nj < 4; nj++)
          acc[mi][nj] = __builtin_amdgcn_mfma_f32_16x16x32_bf16(af[mi], bf[nj], acc[mi][nj], 0, 0, 0);
    }
    __syncthreads();
  }

  if (mode == 3) {
    float* out = (float*)outp;
#pragma unroll
    for (int mi = 0; mi < 4; mi++)
#pragma unroll
      for (int nj = 0; nj < 4; nj++)
#pragma unroll
        for (int r = 0; r < 4; r++) {
          int mg = m0 + wm * 64 + mi * 16 + l4 * 4 + r;
          int ng = n0 + wn * 64 + nj * 16 + l15;
          out[(size_t)mg * 1024 + ng] = acc[mi][nj][r] + bias[ng];
        }
  } else if (mode == 2) {
    u16* vt = (u16*)outp;
#pragma unroll
    for (int mi = 0; mi < 4; mi++)
#pragma unroll
      for (int nj = 0; nj < 4; nj++) {
        int ng = n0 + wn * 64 + nj * 16 + l15;
        int h = ng >> 6, d = ng & 63;
        int mgb = m0 + wm * 64 + mi * 16 + l4 * 4;
        int b = mgb >> 11, s = mgb & 2047;
        float bs = bias[ng];
        u16x4 pk;
#pragma unroll
        for (int r = 0; r < 4; r++) pk[r] = f2bf(acc[mi][nj][r] + bs);
        *(u16x4*)(vt + ((size_t)(b * Hn + h) * DHn + d) * Sn + s) = pk;
      }
  } else {
    u16* oh = (u16*)outp;
    float sc = (mode == 0) ? 0.125f : 1.0f;
#pragma unroll
    for (int mi = 0; mi < 4; mi++)
#pragma unroll
      for (int nj = 0; nj < 4; nj++) {
        int ng = n0 + wn * 64 + nj * 16 + l15;
        int h = ng >> 6, d = ng & 63;
        float bs = bias[ng];
#pragma unroll
        for (int r = 0; r < 4; r++) {
          int mg = m0 + wm * 64 + mi * 16 + l4 * 4 + r;
          int b = mg >> 11, s = mg & 2047;
          oh[((size_t)(b * Hn + h) * Sn + s) * DHn + d] = f2bf((acc[mi][nj][r] + bs) * sc);
        }
      }
  }
}

// ---------------------------------------------------------------------------
// Attention: block = (qt, h, b), 256 thr / 4 waves; QBLK=128, KBLK=64.
// S^T = mfma(K, Q) so key-reduction is in-lane + shfl_xor(16,32).
// Pass1: online (m,l). Pass2: recompute, write P bf16 to LDS, store attn f32,
// ctx^T += mfma(Vt, P^T). LDS rows are 128B, XOR-16B-granule swizzled.
// ---------------------------------------------------------------------------
#define Q_OFF 0
#define K_OFF 16384
#define V_OFF 24576
#define P_OFF 32768
#define L_OFF 49152

__global__ __launch_bounds__(256) void attn_k(
    const u16* __restrict__ qh, const u16* __restrict__ kh,
    const u16* __restrict__ vt, const float* __restrict__ maskT,
    const int* __restrict__ flags, float* __restrict__ attn,
    u16* __restrict__ ctxc) {
  __shared__ __align__(16) char sm[49152 + 512];
  int qt = blockIdx.x, h = blockIdx.y, b = blockIdx.z;
  int bh = b * Hn + h;
  int tid = threadIdx.x, w = tid >> 6, l = tid & 63, l15 = l & 15, l4 = l >> 4;

  const u16* Qg = qh + ((size_t)bh * Sn + qt * 128) * DHn;
  const u16* Kg = kh + (size_t)bh * Sn * DHn;
  const u16* Vg = vt + (size_t)bh * DHn * Sn;

  // stage Q tile [128][64] (swizzled)
  for (int rr = 0; rr < 4; rr++) {
    int gid = rr * 256 + tid, row = gid >> 3, g = gid & 7;
    i32x4 v = *(const i32x4*)(Qg + (size_t)row * DHn + g * 8);
    *(i32x4*)(sm + Q_OFF + row * 128 + ((g * 16) ^ ((row & 7) << 4))) = v;
  }

  float m_run[2] = {-1e30f, -1e30f}, l_run[2] = {0.f, 0.f};

  // ---------------- pass 1: running (m, l) ----------------
  for (int t = 0; t < 32; t++) {
    int k0 = t * 64;
    for (int rr = 0; rr < 2; rr++) {
      int gid = rr * 256 + tid, row = gid >> 3, g = gid & 7;
      i32x4 v = *(const i32x4*)(Kg + (size_t)(k0 + row) * DHn + g * 8);
      *(i32x4*)(sm + K_OFF + row * 128 + ((g * 16) ^ ((row & 7) << 4))) = v;
    }
    __syncthreads();
    f32x4 s[4][2] = {};
#pragma unroll
    for (int kk = 0; kk < 2; kk++) {
      int kb = kk * 64 + l4 * 16;
      bf16x8 a[4], bq[2];
#pragma unroll
      for (int mi = 0; mi < 4; mi++) {
        int row = mi * 16 + l15;
        a[mi] = *(const bf16x8*)(sm + K_OFF + row * 128 + (kb ^ ((row & 7) << 4)));
      }
#pragma unroll
      for (int ni = 0; ni < 2; ni++) {
        int row = w * 32 + ni * 16 + l15;
        bq[ni] = *(const bf16x8*)(sm + Q_OFF + row * 128 + (kb ^ ((row & 7) << 4)));
      }
#pragma unroll
      for (int mi = 0; mi < 4; mi++)
#pragma unroll
        for (int ni = 0; ni < 2; ni++)
          s[mi][ni] = __builtin_amdgcn_mfma_f32_16x16x32_bf16(a[mi], bq[ni], s[mi][ni], 0, 0, 0);
    }
    if (!flags[(b * 32 + t) * 16 + qt]) {
      for (int mi = 0; mi < 4; mi++)
        for (int ni = 0; ni < 2; ni++)
          for (int r = 0; r < 4; r++) {
            int sk = k0 + mi * 16 + l4 * 4 + r;
            int sq = qt * 128 + w * 32 + ni * 16 + l15;
            float mv = maskT[((size_t)b * Sn + sk) * Sn + sq];
            s[mi][ni][r] = s[mi][ni][r] * mv - 1e6f * (1.f - mv);
          }
    }
#pragma unroll
    for (int ni = 0; ni < 2; ni++) {
      float tmax = -1e30f;
#pragma unroll
      for (int mi = 0; mi < 4; mi++)
#pragma unroll
        for (int r = 0; r < 4; r++) tmax = fmaxf(tmax, s[mi][ni][r]);
      tmax = fmaxf(tmax, __shfl_xor(tmax, 16));
      tmax = fmaxf(tmax, __shfl_xor(tmax, 32));
      float mn = fmaxf(m_run[ni], tmax);
      float sum = 0.f;
#pragma unroll
      for (int mi = 0; mi < 4; mi++)
#pragma unroll
        for (int r = 0; r < 4; r++) sum += __expf(s[mi][ni][r] - mn);
      sum += __shfl_xor(sum, 16);
      sum += __shfl_xor(sum, 32);
      l_run[ni] = l_run[ni] * __expf(m_run[ni] - mn) + sum;
      m_run[ni] = mn;
    }
    __syncthreads();
  }

  float linv[2] = {1.f / l_run[0], 1.f / l_run[1]};
  if (l4 == 0) {
    ((float*)(sm + L_OFF))[w * 32 + l15] = linv[0];
    ((float*)(sm + L_OFF))[w * 32 + 16 + l15] = linv[1];
  }

  // ---------------- pass 2: P + attn store + PV ----------------
  f32x4 ctx[4][2] = {};
  for (int t = 0; t < 32; t++) {
    int k0 = t * 64;
    for (int rr = 0; rr < 2; rr++) {
      int gid = rr * 256 + tid, row = gid >> 3, g = gid & 7;
      i32x4 v = *(const i32x4*)(Kg + (size_t)(k0 + row) * DHn + g * 8);
      *(i32x4*)(sm + K_OFF + row * 128 + ((g * 16) ^ ((row & 7) << 4))) = v;
    }
    for (int rr = 0; rr < 2; rr++) {
      int gid = rr * 256 + tid, row = gid >> 3, g = gid & 7;
      i32x4 v = *(const i32x4*)(Vg + (size_t)row * Sn + k0 + g * 8);
      *(i32x4*)(sm + V_OFF + row * 128 + ((g * 16) ^ ((row & 7) << 4))) = v;
    }
    __syncthreads();
    f32x4 s[4][2] = {};
#pragma unroll
    for (int kk = 0; kk < 2; kk++) {
      int kb = kk * 64 + l4 * 16;
      bf16x8 a[4], bq[2];
#pragma unroll
      for (int mi = 0; mi < 4; mi++) {
        int row = mi * 16 + l15;
        a[mi] = *(const bf16x8*)(sm + K_OFF + row * 128 + (kb ^ ((row & 7) << 4)));
      }
#pragma unroll
      for (int ni = 0; ni < 2; ni++) {
        int row = w * 32 + ni * 16 + l15;
        bq[ni] = *(const bf16x8*)(sm + Q_OFF + row * 128 + (kb ^ ((row & 7) << 4)));
      }
#pragma unroll
      for (int mi = 0; mi < 4; mi++)
#pragma unroll
        for (int ni = 0; ni < 2; ni++)
          s[mi][ni] = __builtin_amdgcn_mfma_f32_16x16x32_bf16(a[mi], bq[ni], s[mi][ni], 0, 0, 0);
    }
    if (!flags[(b * 32 + t) * 16 + qt]) {
      for (int mi = 0; mi < 4; mi++)
        for (int ni = 0; ni < 2; ni++)
          for (int r = 0; r < 4; r++) {
            int sk = k0 + mi * 16 + l4 * 4 + r;
            int sq = qt * 128 + w * 32 + ni * 16 + l15;
            float mv = maskT[((size_t)b * Sn + sk) * Sn + sq];
            s[mi][ni][r] = s[mi][ni][r] * mv - 1e6f * (1.f - mv);
          }
    }
    // write P^T tile (as PT[q][key], bf16, swizzled)
#pragma unroll
    for (int ni = 0; ni < 2; ni++) {
      int q = w * 32 + ni * 16 + l15;
#pragma unroll
      for (int mi = 0; mi < 4; mi++) {
        u16x4 pk;
#pragma unroll
        for (int r = 0; r < 4; r++) pk[r] = f2bf(__expf(s[mi][ni][r] - m_run[ni]));
        int kb = mi * 32 + l4 * 8;
        *(u16x4*)(sm + P_OFF + q * 128 + (kb ^ ((q & 7) << 4))) = pk;
      }
    }
    __syncthreads();
    // PV: ctx^T += Vt x P^T
#pragma unroll
    for (int kk = 0; kk < 2; kk++) {
      int kb = kk * 64 + l4 * 16;
      bf16x8 av[4], bp[2];
#pragma unroll
      for (int mi = 0; mi < 4; mi++) {
        int row = mi * 16 + l15;
        av[mi] = *(const bf16x8*)(sm + V_OFF + row * 128 + (kb ^ ((row & 7) << 4)));
      }
#pragma unroll
      for (int ni = 0; ni < 2; ni++) {
        int q = w * 32 + ni * 16 + l15;
        bp[ni] = *(const bf16x8*)(sm + P_OFF + q * 128 + (kb ^ ((q & 7) << 4)));
      }
#pragma unroll
      for (int mi = 0; mi < 4; mi++)
#pragma unroll
        for (int ni = 0; ni < 2; ni++)
          ctx[mi][ni] = __builtin_amdgcn_mfma_f32_16x16x32_bf16(av[mi], bp[ni], ctx[mi][ni], 0, 0, 0);
    }
    // attn_weights store (coalesced, f32, x 1/l)
    {
      int q = tid >> 1, hf = tid & 1;
      float li = ((const float*)(sm + L_OFF))[q];
      float* dst = attn + ((size_t)bh * Sn + qt * 128 + q) * Sn + k0 + hf * 32;
#pragma unroll
      for (int c4 = 0; c4 < 4; c4++) {
        int kb = hf * 64 + c4 * 16;
        u16x8 pv = *(const u16x8*)(sm + P_OFF + q * 128 + (kb ^ ((q & 7) << 4)));
        f32x4 o0, o1;
#pragma unroll
        for (int j = 0; j < 4; j++) { o0[j] = bf2f(pv[j]) * li; o1[j] = bf2f(pv[4 + j]) * li; }
        *(f32x4*)(dst + c4 * 8) = o0;
        *(f32x4*)(dst + c4 * 8 + 4) = o1;
      }
    }
    __syncthreads();
  }

  // ctx epilogue: normalize, LDS round-trip, coalesced bf16 store to concat
#pragma unroll
  for (int ni = 0; ni < 2; ni++) {
    int q = w * 32 + ni * 16 + l15;
#pragma unroll
    for (int mi = 0; mi < 4; mi++) {
      u16x4 ck;
#pragma unroll
      for (int r = 0; r < 4; r++) ck[r] = f2bf(ctx[mi][ni][r] * linv[ni]);
      int db = mi * 32 + l4 * 8;
      *(u16x4*)(sm + P_OFF + q * 128 + (db ^ ((q & 7) << 4))) = ck;
    }
  }
  __syncthreads();
  {
    int q = tid >> 1, hf = tid & 1;
    u16* dst = ctxc + ((size_t)b * Sn + qt * 128 + q) * Dn + h * DHn + hf * 32;
#pragma unroll
    for (int c4 = 0; c4 < 4; c4++) {
      int db = hf * 64 + c4 * 16;
      i32x4 v = *(const i32x4*)(sm + P_OFF + q * 128 + (db ^ ((q & 7) << 4)));
      *(i32x4*)(dst + c4 * 8) = v;
    }
  }
}

// ---------------------------------------------------------------------------
extern "C" void kernel_launch(void* const* d_in, const int* in_sizes, int n_in,
                              void* d_out, int out_size, void* d_ws, size_t ws_size,
                              hipStream_t stream) {
  const float* v_f  = (const float*)d_in[0];
  const float* k_f  = (const float*)d_in[1];
  const float* q_f  = (const float*)d_in[2];
  const float* mask = (const float*)d_in[3];
  const float* wq_w = (const float*)d_in[4];
  const float* wq_b = (const float*)d_in[5];
  const float* wk_w = (const float*)d_in[6];
  const float* wk_b = (const float*)d_in[7];
  const float* wv_w = (const float*)d_in[8];
  const float* wv_b = (const float*)d_in[9];
  const float* wo_w = (const float*)d_in[10];
  const float* wo_b = (const float*)d_in[11];

  char* ws = (char*)d_ws;
  // workspace layout (bytes)
  u16*   qbf  = (u16*)(ws + 0);            // 16.78 MB
  u16*   kbf  = (u16*)(ws + 16777216);
  u16*   vbf  = (u16*)(ws + 33554432);
  u16*   wqT  = (u16*)(ws + 50331648);     // 2.1 MB each
  u16*   wkT  = (u16*)(ws + 52428800);
  u16*   wvT  = (u16*)(ws + 54525952);
  u16*   woT  = (u16*)(ws + 56623104);
  u16*   qhp  = (u16*)(ws + 58720256);     // Q/8 head-split
  u16*   khp  = (u16*)(ws + 75497472);
  u16*   vtp  = (u16*)(ws + 92274688);     // V^T per head
  u16*   ctxc = (u16*)(ws + 109051904);    // concat ctx bf16
  float* mT   = (float*)(ws + 125829120);  // 67.1 MB
  int*   flg  = (int*)(ws + 192937984);    // 2048 ints

  float* out  = (float*)d_out;
  float* attn = out + (size_t)Bn * Sn * Dn;   // 8388608 offset

  cast_k<<<4096, 256, 0, stream>>>(q_f, qbf);
  cast_k<<<4096, 256, 0, stream>>>(k_f, kbf);
  cast_k<<<4096, 256, 0, stream>>>(v_f, vbf);
  castWT_k<<<dim3(16, 16), 256, 0, stream>>>(wq_w, wqT);
  castWT_k<<<dim3(16, 16), 256, 0, stream>>>(wk_w, wkT);
  castWT_k<<<dim3(16, 16), 256, 0, stream>>>(wv_w, wvT);
  castWT_k<<<dim3(16, 16), 256, 0, stream>>>(wo_w, woT);
  maskT_k<<<dim3(32, 32, 4), 256, 0, stream>>>(mask, mT);
  flags_k<<<dim3(16, 32, 4), 256, 0, stream>>>(mT, flg);

  gemm_k<<<dim3(8, 64), 256, 0, stream>>>(qbf, wqT, wq_b, (void*)qhp, 0);
  gemm_k<<<dim3(8, 64), 256, 0, stream>>>(kbf, wkT, wk_b, (void*)khp, 1);
  gemm_k<<<dim3(8, 64), 256, 0, stream>>>(vbf, wvT, wv_b, (void*)vtp, 2);

  attn_k<<<dim3(16, 16, 4), 256, 0, stream>>>(qhp, khp, vtp, mT, flg, attn, ctxc);

  gemm_k<<<dim3(8, 64), 256, 0, stream>>>(ctxc, woT, wo_b, (void*)out, 3);
}

// Round 2
// 804.806 us; speedup vs baseline: 1.1685x; 1.1685x over previous
//
#include <hip/hip_runtime.h>

// ---------------------------------------------------------------------------
// CustomizedMultiHeadAttention: B=4 S=2048 D=1024 H=16 DH=64
// out [B,S,D] f32  +  attn_weights [B,H,S,S] f32, concat in d_out.
// v2: single fused cast launches, no maskT, attn with Q-in-regs, dbuf K/V via
//     global_load_lds, 1 barrier/tile (pass1) / 2 (pass2), reg->global stores.
// ---------------------------------------------------------------------------

typedef unsigned short u16;
typedef unsigned int   u32;
typedef u16   u16x4  __attribute__((ext_vector_type(4)));
typedef u16   u16x8  __attribute__((ext_vector_type(8)));
typedef int   i32x4  __attribute__((ext_vector_type(4)));
typedef float f32x4  __attribute__((ext_vector_type(4)));
typedef __bf16 bf16x8 __attribute__((ext_vector_type(8)));

#define GLDS16(gp, lp)                                                         \
  __builtin_amdgcn_global_load_lds(                                            \
      (const __attribute__((address_space(1))) void*)(gp),                     \
      (__attribute__((address_space(3))) void*)(lp), 16, 0, 0)

__device__ __forceinline__ u16 f2bf(float x) {
  __bf16 h = (__bf16)x;                       // RNE; compiler can pack-convert
  union { __bf16 h; u16 u; } c; c.h = h; return c.u;
}

static const int Bn = 4, Sn = 2048, Dn = 1024, Hn = 16, DHn = 64;

// ------------------------------------------------- fused cast q,k,v f32->bf16
__global__ __launch_bounds__(256) void cast3_k(const float* __restrict__ q,
                                               const float* __restrict__ k,
                                               const float* __restrict__ v,
                                               u16* __restrict__ out) {
  int which = blockIdx.x >> 12;               // 4096 blocks per tensor
  size_t li = (size_t)(blockIdx.x & 4095) * 256 + threadIdx.x;
  const float* src = which == 0 ? q : which == 1 ? k : v;
  const f32x4* p = (const f32x4*)src + li * 2;
  f32x4 a = p[0], b = p[1];
  u16x8 r;
  r[0]=f2bf(a[0]); r[1]=f2bf(a[1]); r[2]=f2bf(a[2]); r[3]=f2bf(a[3]);
  r[4]=f2bf(b[0]); r[5]=f2bf(b[1]); r[6]=f2bf(b[2]); r[7]=f2bf(b[3]);
  *((u16x8*)(out + (size_t)which * 8388608) + li) = r;
}

// --------------------------- fused weight cast+transpose x4: WT[n][k]=W[k][n]
__global__ __launch_bounds__(256) void castWT4_k(const float* __restrict__ w0,
                                                 const float* __restrict__ w1,
                                                 const float* __restrict__ w2,
                                                 const float* __restrict__ w3,
                                                 u16* __restrict__ WTb) {
  __shared__ u16 tile[64][72];
  int z = blockIdx.z;
  const float* W = z == 0 ? w0 : z == 1 ? w1 : z == 2 ? w2 : w3;
  u16* WT = WTb + (size_t)z * 1048576;
  int bx = blockIdx.x, by = blockIdx.y, t = threadIdx.x;
  for (int rr = 0; rr < 4; rr++) {
    int r = rr * 16 + (t >> 4);     // k-local
    int c = (t & 15) * 4;           // n-local
    float4 v = *(const float4*)(W + (size_t)(by * 64 + r) * 1024 + bx * 64 + c);
    tile[c + 0][r] = f2bf(v.x); tile[c + 1][r] = f2bf(v.y);
    tile[c + 2][r] = f2bf(v.z); tile[c + 3][r] = f2bf(v.w);
  }
  __syncthreads();
  for (int rr = 0; rr < 2; rr++) {
    int gid = rr * 256 + t;
    int r = gid >> 3, g = gid & 7;  // r = n-local
    u16x8 v = *(const u16x8*)&tile[r][g * 8];
    *(u16x8*)(WT + (size_t)(bx * 64 + r) * 1024 + by * 64 + g * 8) = v;
  }
}

// --------------- all-ones flags per [kt:64 sk x qt:128 sq] tile, from mask
__global__ __launch_bounds__(256) void flags_k(const float* __restrict__ mask,
                                               int* __restrict__ flags) {
  __shared__ int ok_s;
  int t = threadIdx.x;
  if (t == 0) ok_s = 1;
  __syncthreads();
  int qt = blockIdx.x, kt = blockIdx.y, b = blockIdx.z;
  const float* base = mask + ((size_t)b * Sn + qt * 128) * Sn + kt * 64;
  int r = t >> 1, c0 = (t & 1) * 32;
  const float* p = base + (size_t)r * Sn + c0;
  bool ok = true;
  for (int i = 0; i < 8; i++) {
    float4 v = *(const float4*)(p + i * 4);
    ok = ok && (v.x == 1.0f) && (v.y == 1.0f) && (v.z == 1.0f) && (v.w == 1.0f);
  }
  if (!ok) atomicAnd(&ok_s, 0);
  __syncthreads();
  if (t == 0) flags[(b * 32 + kt) * 16 + qt] = ok_s;
}

// ---------------------------------------------------------------------------
// GEMM core: C[8192x1024] = A @ BT^T + bias. 128x128 tile, BK=64, 4 waves,
// global_load_lds w=16, XOR-swizzled LDS (pre-swizzled global source).
// mode 0: Q head-split bf16 *0.125 ; 1: K head-split ; 2: V -> vt[b][h][d][s]
// mode 3: f32 flat out (+bias)
// ---------------------------------------------------------------------------
__device__ __forceinline__ void gemm_body(const u16* __restrict__ A,
                                          const u16* __restrict__ BT,
                                          const float* __restrict__ bias,
                                          void* __restrict__ outp, int mode,
                                          int nt, int mt, char* sm) {
  const int K = 1024;
  int m0 = mt * 128, n0 = nt * 128;
  int tid = threadIdx.x, w = tid >> 6, l = tid & 63, l15 = l & 15, l4 = l >> 4;
  int wm = w >> 1, wn = w & 1;

  size_t goff_a[4], goff_b[4];
  int lbase[4];
  for (int i = 0; i < 4; i++) {
    int gi = (w * 4 + i) * 64 + l;
    int row = gi >> 3, g = gi & 7;
    int gx = g ^ (row & 7);
    goff_a[i] = (size_t)(m0 + row) * K + gx * 8;
    goff_b[i] = (size_t)(n0 + row) * K + gx * 8;
    lbase[i] = (w * 4 + i) * 1024;
  }

  f32x4 acc[4][4] = {};
  for (int t = 0; t < 16; t++) {
    int k0 = t * 64;
    for (int i = 0; i < 4; i++) {
      GLDS16(A + goff_a[i] + k0, sm + lbase[i]);
      GLDS16(BT + goff_b[i] + k0, sm + 16384 + lbase[i]);
    }
    __syncthreads();
#pragma unroll
    for (int kk = 0; kk < 2; kk++) {
      int kb = kk * 64 + l4 * 16;
      bf16x8 af[4], bf[4];
#pragma unroll
      for (int mi = 0; mi < 4; mi++) {
        int row = wm * 64 + mi * 16 + l15;
        af[mi] = *(const bf16x8*)(sm + row * 128 + (kb ^ ((row & 7) << 4)));
      }
#pragma unroll
      for (int nj = 0; nj < 4; nj++) {
        int row = wn * 64 + nj * 16 + l15;
        bf[nj] = *(const bf16x8*)(sm + 16384 + row * 128 + (kb ^ ((row & 7) << 4)));
      }
#pragma unroll
      for (int mi = 0; mi < 4; mi++)
#pragma unroll
        for (int nj = 0; nj < 4; nj++)
          acc[mi][nj] = __builtin_amdgcn_mfma_f32_16x16x32_bf16(af[mi], bf[nj], acc[mi][nj], 0, 0, 0);
    }
    __syncthreads();
  }

  if (mode == 3) {
    float* out = (float*)outp;
#pragma unroll
    for (int mi = 0; mi < 4; mi++)
#pragma unroll
      for (int nj = 0; nj < 4; nj++)
#pragma unroll
        for (int r = 0; r < 4; r++) {
          int mg = m0 + wm * 64 + mi * 16 + l4 * 4 + r;
          int ng = n0 + wn * 64 + nj * 16 + l15;
          out[(size_t)mg * 1024 + ng] = acc[mi][nj][r] + bias[ng];
        }
  } else if (mode == 2) {
    u16* vt = (u16*)outp;
#pragma unroll
    for (int mi = 0; mi < 4; mi++)
#pragma unroll
      for (int nj = 0; nj < 4; nj++) {
        int ng = n0 + wn * 64 + nj * 16 + l15;
        int h = ng >> 6, d = ng & 63;
        int mgb = m0 + wm * 64 + mi * 16 + l4 * 4;
        int b = mgb >> 11, s = mgb & 2047;
        float bs = bias[ng];
        u16x4 pk;
#pragma unroll
        for (int r = 0; r < 4; r++) pk[r] = f2bf(acc[mi][nj][r] + bs);
        *(u16x4*)(vt + ((size_t)(b * Hn + h) * DHn + d) * Sn + s) = pk;
      }
  } else {
    u16* oh = (u16*)outp;
    float sc = (mode == 0) ? 0.125f : 1.0f;
#pragma unroll
    for (int mi = 0; mi < 4; mi++)
#pragma unroll
      for (int nj = 0; nj < 4; nj++) {
        int ng = n0 + wn * 64 + nj * 16 + l15;
        int h = ng >> 6, d = ng & 63;
        float bs = bias[ng];
#pragma unroll
        for (int r = 0; r < 4; r++) {
          int mg = m0 + wm * 64 + mi * 16 + l4 * 4 + r;
          int b = mg >> 11, s = mg & 2047;
          oh[((size_t)(b * Hn + h) * Sn + s) * DHn + d] = f2bf((acc[mi][nj][r] + bs) * sc);
        }
      }
  }
}

__global__ __launch_bounds__(256) void gemm_k(const u16* __restrict__ A,
                                              const u16* __restrict__ BT,
                                              const float* __restrict__ bias,
                                              void* __restrict__ outp, int mode) {
  __shared__ __align__(16) char sm[32768];
  gemm_body(A, BT, bias, outp, mode, blockIdx.x, blockIdx.y, sm);
}

// fused QKV projection: z selects {Q,K,V}; A/BT/out are contiguous slabs
__global__ __launch_bounds__(256) void gemm3_k(const u16* __restrict__ Ab,
                                               const u16* __restrict__ BTb,
                                               const float* __restrict__ b0,
                                               const float* __restrict__ b1,
                                               const float* __restrict__ b2,
                                               u16* __restrict__ outb) {
  __shared__ __align__(16) char sm[32768];
  int z = blockIdx.z;
  const u16* A = Ab + (size_t)z * 8388608;
  const u16* BT = BTb + (size_t)z * 1048576;
  const float* bias = z == 0 ? b0 : z == 1 ? b1 : b2;
  u16* out = outb + (size_t)z * 8388608;
  gemm_body(A, BT, bias, (void*)out, z, blockIdx.x, blockIdx.y, sm);
}

// ---------------------------------------------------------------------------
// Attention. block=(qt,h,b), 4 waves. QBLK=128 (32 q-rows/wave), KBLK=64.
// S^T = mfma(K, Q): lane(l15,l4) holds s[mi][ni][r] at
//   sq = w*32+ni*16+l15 , sk = k0+mi*16+l4*4+r  -> key-reduce = in-lane + 2 shfl.
// Q-frags in registers (loop-invariant). K/V double-buffered, staged with
// global_load_lds (pre-swizzled source). Pass1: 1 barrier/tile. Pass2: 2.
// attn stored directly from registers (f32, 64B-coalesced).
// LDS: K0 8K | K1 8K | V0 8K | V1 8K | P 16K  = 48KB -> 3 blocks/CU.
// ---------------------------------------------------------------------------
#define K0_OFF 0
#define K1_OFF 8192
#define V0_OFF 16384
#define V1_OFF 24576
#define P_OFF  32768

__global__ __launch_bounds__(256) void attn_k(
    const u16* __restrict__ qh, const u16* __restrict__ kh,
    const u16* __restrict__ vt, const float* __restrict__ mask,
    const int* __restrict__ flags, float* __restrict__ attn,
    u16* __restrict__ ctxc) {
  __shared__ __align__(16) char sm[49152];
  int qt = blockIdx.x, h = blockIdx.y, b = blockIdx.z;
  int bh = b * Hn + h;
  int tid = threadIdx.x, w = tid >> 6, l = tid & 63, l15 = l & 15, l4 = l >> 4;

  const u16* Qg = qh + ((size_t)bh * Sn + qt * 128) * DHn;
  const u16* Kg = kh + (size_t)bh * Sn * DHn;
  const u16* Vg = vt + (size_t)bh * DHn * Sn;
  const float* Mg = mask + (size_t)b * Sn * Sn + (size_t)(qt * 128) * Sn;

  // staging source offsets (pre-swizzled granule): gid = i*256+tid
  int srow[2], sgx8[2], sdst[2];
  for (int i = 0; i < 2; i++) {
    int gid = i * 256 + tid, row = gid >> 3, g = gid & 7;
    srow[i] = row; sgx8[i] = (g ^ (row & 7)) * 8; sdst[i] = gid * 16;
  }
#define STAGE_K(t, buf)                                                        \
  for (int i = 0; i < 2; i++)                                                  \
    GLDS16(Kg + (size_t)((t) * 64 + srow[i]) * DHn + sgx8[i], sm + (buf) + sdst[i]);
#define STAGE_V(t, buf)                                                        \
  for (int i = 0; i < 2; i++)                                                  \
    GLDS16(Vg + (size_t)srow[i] * Sn + (t) * 64 + sgx8[i], sm + (buf) + sdst[i]);

  // Q fragments in registers (B-operand layout: col=sq(l15), k=d(l4*8+j))
  bf16x8 qf[2][2];
#pragma unroll
  for (int ni = 0; ni < 2; ni++)
#pragma unroll
    for (int kk = 0; kk < 2; kk++)
      qf[ni][kk] = *(const bf16x8*)(Qg + (size_t)(w * 32 + ni * 16 + l15) * DHn + kk * 32 + l4 * 8);

  float m_run[2] = {-1e30f, -1e30f}, l_run[2] = {0.f, 0.f};

  // ---------------- pass 1: running (m, l); 1 barrier/tile ----------------
  STAGE_K(0, K0_OFF);
  for (int t = 0; t < 32; t++) {
    int kcur = (t & 1) ? K1_OFF : K0_OFF;
    __syncthreads();                       // drains stage(t) -> K[cur] visible
    if (t < 31) { int knxt = (t & 1) ? K0_OFF : K1_OFF; STAGE_K(t + 1, knxt); }
    f32x4 s[4][2] = {};
#pragma unroll
    for (int kk = 0; kk < 2; kk++) {
      int kb = kk * 64 + l4 * 16;
      bf16x8 a[4];
#pragma unroll
      for (int mi = 0; mi < 4; mi++) {
        int row = mi * 16 + l15;
        a[mi] = *(const bf16x8*)(sm + kcur + row * 128 + (kb ^ ((row & 7) << 4)));
      }
#pragma unroll
      for (int mi = 0; mi < 4; mi++)
#pragma unroll
        for (int ni = 0; ni < 2; ni++)
          s[mi][ni] = __builtin_amdgcn_mfma_f32_16x16x32_bf16(a[mi], qf[ni][kk], s[mi][ni], 0, 0, 0);
    }
    if (!flags[(b * 32 + t) * 16 + qt]) {
#pragma unroll
      for (int ni = 0; ni < 2; ni++) {
        const float* mrow = Mg + (size_t)(w * 32 + ni * 16 + l15) * Sn + t * 64;
#pragma unroll
        for (int mi = 0; mi < 4; mi++) {
          f32x4 mv = *(const f32x4*)(mrow + mi * 16 + l4 * 4);
#pragma unroll
          for (int r = 0; r < 4; r++)
            s[mi][ni][r] = s[mi][ni][r] * mv[r] - 1e6f * (1.f - mv[r]);
        }
      }
    }
#pragma unroll
    for (int ni = 0; ni < 2; ni++) {
      float tmax = -1e30f;
#pragma unroll
      for (int mi = 0; mi < 4; mi++)
#pragma unroll
        for (int r = 0; r < 4; r++) tmax = fmaxf(tmax, s[mi][ni][r]);
      tmax = fmaxf(tmax, __shfl_xor(tmax, 16));
      tmax = fmaxf(tmax, __shfl_xor(tmax, 32));
      float mn = fmaxf(m_run[ni], tmax);
      float sum = 0.f;
#pragma unroll
      for (int mi = 0; mi < 4; mi++)
#pragma unroll
        for (int r = 0; r < 4; r++) sum += __expf(s[mi][ni][r] - mn);
      sum += __shfl_xor(sum, 16);
      sum += __shfl_xor(sum, 32);
      l_run[ni] = l_run[ni] * __expf(m_run[ni] - mn) + sum;
      m_run[ni] = mn;
    }
  }
  float linv[2] = {1.f / l_run[0], 1.f / l_run[1]};

  // ---------------- pass 2: attn store + PV; 2 barriers/tile ----------------
  f32x4 ctx[4][2] = {};
  STAGE_K(0, K0_OFF);
  STAGE_V(0, V0_OFF);
  for (int t = 0; t < 32; t++) {
    int kcur = (t & 1) ? K1_OFF : K0_OFF;
    int vcur = (t & 1) ? V1_OFF : V0_OFF;
    __syncthreads();                       // sync1: stages drained/visible
    f32x4 s[4][2] = {};
#pragma unroll
    for (int kk = 0; kk < 2; kk++) {
      int kb = kk * 64 + l4 * 16;
      bf16x8 a[4];
#pragma unroll
      for (int mi = 0; mi < 4; mi++) {
        int row = mi * 16 + l15;
        a[mi] = *(const bf16x8*)(sm + kcur + row * 128 + (kb ^ ((row & 7) << 4)));
      }
#pragma unroll
      for (int mi = 0; mi < 4; mi++)
#pragma unroll
        for (int ni = 0; ni < 2; ni++)
          s[mi][ni] = __builtin_amdgcn_mfma_f32_16x16x32_bf16(a[mi], qf[ni][kk], s[mi][ni], 0, 0, 0);
    }
    if (!flags[(b * 32 + t) * 16 + qt]) {
#pragma unroll
      for (int ni = 0; ni < 2; ni++) {
        const float* mrow = Mg + (size_t)(w * 32 + ni * 16 + l15) * Sn + t * 64;
#pragma unroll
        for (int mi = 0; mi < 4; mi++) {
          f32x4 mv = *(const f32x4*)(mrow + mi * 16 + l4 * 4);
#pragma unroll
          for (int r = 0; r < 4; r++)
            s[mi][ni][r] = s[mi][ni][r] * mv[r] - 1e6f * (1.f - mv[r]);
        }
      }
    }
    // s := exp(s - m)  (final m from pass 1)
#pragma unroll
    for (int ni = 0; ni < 2; ni++)
#pragma unroll
      for (int mi = 0; mi < 4; mi++)
#pragma unroll
        for (int r = 0; r < 4; r++) s[mi][ni][r] = __expf(s[mi][ni][r] - m_run[ni]);
    // P -> LDS (bf16, [128 sq][64 sk], swizzled)
#pragma unroll
    for (int ni = 0; ni < 2; ni++) {
      int q = w * 32 + ni * 16 + l15;
#pragma unroll
      for (int mi = 0; mi < 4; mi++) {
        u16x4 pk;
#pragma unroll
        for (int r = 0; r < 4; r++) pk[r] = f2bf(s[mi][ni][r]);
        int kb = mi * 32 + l4 * 8;
        *(u16x4*)(sm + P_OFF + q * 128 + (kb ^ ((q & 7) << 4))) = pk;
      }
    }
    __syncthreads();                       // sync2: P visible
    if (t < 31) {
      int knxt = (t & 1) ? K0_OFF : K1_OFF;
      int vnxt = (t & 1) ? V0_OFF : V1_OFF;
      STAGE_K(t + 1, knxt);
      STAGE_V(t + 1, vnxt);
    }
    // attn store, direct from registers (drains at next sync1; PV overlaps)
#pragma unroll
    for (int ni = 0; ni < 2; ni++) {
      float* arow = attn + ((size_t)bh * Sn + qt * 128 + w * 32 + ni * 16 + l15) * Sn + t * 64;
#pragma unroll
      for (int mi = 0; mi < 4; mi++) {
        f32x4 o;
#pragma unroll
        for (int r = 0; r < 4; r++) o[r] = s[mi][ni][r] * linv[ni];
        *(f32x4*)(arow + mi * 16 + l4 * 4) = o;
      }
    }
    // PV: ctx^T += Vt x P^T
#pragma unroll
    for (int kk = 0; kk < 2; kk++) {
      int kb = kk * 64 + l4 * 16;
      bf16x8 av[4], bp[2];
#pragma unroll
      for (int mi = 0; mi < 4; mi++) {
        int row = mi * 16 + l15;
        av[mi] = *(const bf16x8*)(sm + vcur + row * 128 + (kb ^ ((row & 7) << 4)));
      }
#pragma unroll
      for (int ni = 0; ni < 2; ni++) {
        int q = w * 32 + ni * 16 + l15;
        bp[ni] = *(const bf16x8*)(sm + P_OFF + q * 128 + (kb ^ ((q & 7) << 4)));
      }
#pragma unroll
      for (int mi = 0; mi < 4; mi++)
#pragma unroll
        for (int ni = 0; ni < 2; ni++)
          ctx[mi][ni] = __builtin_amdgcn_mfma_f32_16x16x32_bf16(av[mi], bp[ni], ctx[mi][ni], 0, 0, 0);
    }
  }

  // ctx epilogue: normalize, LDS round-trip (reuse P area), coalesced store
  __syncthreads();
#pragma unroll
  for (int ni = 0; ni < 2; ni++) {
    int q = w * 32 + ni * 16 + l15;
#pragma unroll
    for (int mi = 0; mi < 4; mi++) {
      u16x4 ck;
#pragma unroll
      for (int r = 0; r < 4; r++) ck[r] = f2bf(ctx[mi][ni][r] * linv[ni]);
      int db = mi * 32 + l4 * 8;
      *(u16x4*)(sm + P_OFF + q * 128 + (db ^ ((q & 7) << 4))) = ck;
    }
  }
  __syncthreads();
  {
    int q = tid >> 1, hf = tid & 1;
    u16* dst = ctxc + ((size_t)b * Sn + qt * 128 + q) * Dn + h * DHn + hf * 32;
#pragma unroll
    for (int c4 = 0; c4 < 4; c4++) {
      int db = hf * 64 + c4 * 16;
      i32x4 v = *(const i32x4*)(sm + P_OFF + q * 128 + (db ^ ((q & 7) << 4)));
      *(i32x4*)(dst + c4 * 8) = v;
    }
  }
}

// ---------------------------------------------------------------------------
extern "C" void kernel_launch(void* const* d_in, const int* in_sizes, int n_in,
                              void* d_out, int out_size, void* d_ws, size_t ws_size,
                              hipStream_t stream) {
  const float* v_f  = (const float*)d_in[0];
  const float* k_f  = (const float*)d_in[1];
  const float* q_f  = (const float*)d_in[2];
  const float* mask = (const float*)d_in[3];
  const float* wq_w = (const float*)d_in[4];
  const float* wq_b = (const float*)d_in[5];
  const float* wk_w = (const float*)d_in[6];
  const float* wk_b = (const float*)d_in[7];
  const float* wv_w = (const float*)d_in[8];
  const float* wv_b = (const float*)d_in[9];
  const float* wo_w = (const float*)d_in[10];
  const float* wo_b = (const float*)d_in[11];

  char* ws = (char*)d_ws;
  u16*   qbf  = (u16*)(ws + 0);             // q,k,v bf16 slabs (contig)
  u16*   wT   = (u16*)(ws + 50331648);      // wqT,wkT,wvT,woT (contig, 2MB ea)
  u16*   woT  = (u16*)(ws + 56623104);
  u16*   qhp  = (u16*)(ws + 58720256);      // Qh, Kh, Vt slabs (contig, 16MB ea)
  u16*   khp  = (u16*)(ws + 75497472);
  u16*   vtp  = (u16*)(ws + 92274688);
  u16*   ctxc = (u16*)(ws + 109051904);
  int*   flg  = (int*)(ws + 125829120);

  float* out  = (float*)d_out;
  float* attn = out + (size_t)Bn * Sn * Dn;

  cast3_k<<<12288, 256, 0, stream>>>(q_f, k_f, v_f, qbf);
  castWT4_k<<<dim3(16, 16, 4), 256, 0, stream>>>(wq_w, wk_w, wv_w, wo_w, wT);
  flags_k<<<dim3(16, 32, 4), 256, 0, stream>>>(mask, flg);

  gemm3_k<<<dim3(8, 64, 3), 256, 0, stream>>>(qbf, wT, wq_b, wk_b, wv_b, qhp);

  attn_k<<<dim3(16, 16, 4), 256, 0, stream>>>(qhp, khp, vtp, mask, flg, attn, ctxc);

  gemm_k<<<dim3(8, 64), 256, 0, stream>>>(ctxc, woT, wo_b, (void*)out, 3);
}

// Round 3
// 628.382 us; speedup vs baseline: 1.4966x; 1.2808x over previous
//
#include <hip/hip_runtime.h>

// ---------------------------------------------------------------------------
// CustomizedMultiHeadAttention: B=4 S=2048 D=1024 H=16 DH=64
// out [B,S,D] f32  +  attn_weights [B,H,S,S] f32, concat in d_out.
// v3: XCD-chunked block swizzle (GEMMs + attn), pass-2 single barrier
//     (P is wave-private), flag bitmask via ballot, early attn stores.
// ---------------------------------------------------------------------------

typedef unsigned short u16;
typedef unsigned int   u32;
typedef u16   u16x4  __attribute__((ext_vector_type(4)));
typedef u16   u16x8  __attribute__((ext_vector_type(8)));
typedef int   i32x4  __attribute__((ext_vector_type(4)));
typedef float f32x4  __attribute__((ext_vector_type(4)));
typedef __bf16 bf16x8 __attribute__((ext_vector_type(8)));

#define GLDS16(gp, lp)                                                         \
  __builtin_amdgcn_global_load_lds(                                            \
      (const __attribute__((address_space(1))) void*)(gp),                     \
      (__attribute__((address_space(3))) void*)(lp), 16, 0, 0)

__device__ __forceinline__ u16 f2bf(float x) {
  __bf16 h = (__bf16)x;
  union { __bf16 h; u16 u; } c; c.h = h; return c.u;
}

static const int Bn = 4, Sn = 2048, Dn = 1024, Hn = 16, DHn = 64;

// ------------------------------------------------- fused cast q,k,v f32->bf16
__global__ __launch_bounds__(256) void cast3_k(const float* __restrict__ q,
                                               const float* __restrict__ k,
                                               const float* __restrict__ v,
                                               u16* __restrict__ out) {
  int which = blockIdx.x >> 12;
  size_t li = (size_t)(blockIdx.x & 4095) * 256 + threadIdx.x;
  const float* src = which == 0 ? q : which == 1 ? k : v;
  const f32x4* p = (const f32x4*)src + li * 2;
  f32x4 a = p[0], b = p[1];
  u16x8 r;
  r[0]=f2bf(a[0]); r[1]=f2bf(a[1]); r[2]=f2bf(a[2]); r[3]=f2bf(a[3]);
  r[4]=f2bf(b[0]); r[5]=f2bf(b[1]); r[6]=f2bf(b[2]); r[7]=f2bf(b[3]);
  *((u16x8*)(out + (size_t)which * 8388608) + li) = r;
}

// --------------------------- fused weight cast+transpose x4: WT[n][k]=W[k][n]
__global__ __launch_bounds__(256) void castWT4_k(const float* __restrict__ w0,
                                                 const float* __restrict__ w1,
                                                 const float* __restrict__ w2,
                                                 const float* __restrict__ w3,
                                                 u16* __restrict__ WTb) {
  __shared__ u16 tile[64][72];
  int z = blockIdx.z;
  const float* W = z == 0 ? w0 : z == 1 ? w1 : z == 2 ? w2 : w3;
  u16* WT = WTb + (size_t)z * 1048576;
  int bx = blockIdx.x, by = blockIdx.y, t = threadIdx.x;
  for (int rr = 0; rr < 4; rr++) {
    int r = rr * 16 + (t >> 4);
    int c = (t & 15) * 4;
    float4 v = *(const float4*)(W + (size_t)(by * 64 + r) * 1024 + bx * 64 + c);
    tile[c + 0][r] = f2bf(v.x); tile[c + 1][r] = f2bf(v.y);
    tile[c + 2][r] = f2bf(v.z); tile[c + 3][r] = f2bf(v.w);
  }
  __syncthreads();
  for (int rr = 0; rr < 2; rr++) {
    int gid = rr * 256 + t;
    int r = gid >> 3, g = gid & 7;
    u16x8 v = *(const u16x8*)&tile[r][g * 8];
    *(u16x8*)(WT + (size_t)(bx * 64 + r) * 1024 + by * 64 + g * 8) = v;
  }
}

// --------------- all-ones flags per [kt:64 sk x qt:128 sq] tile, from mask
__global__ __launch_bounds__(256) void flags_k(const float* __restrict__ mask,
                                               int* __restrict__ flags) {
  __shared__ int ok_s;
  int t = threadIdx.x;
  if (t == 0) ok_s = 1;
  __syncthreads();
  int qt = blockIdx.x, kt = blockIdx.y, b = blockIdx.z;
  const float* base = mask + ((size_t)b * Sn + qt * 128) * Sn + kt * 64;
  int r = t >> 1, c0 = (t & 1) * 32;
  const float* p = base + (size_t)r * Sn + c0;
  bool ok = true;
  for (int i = 0; i < 8; i++) {
    float4 v = *(const float4*)(p + i * 4);
    ok = ok && (v.x == 1.0f) && (v.y == 1.0f) && (v.z == 1.0f) && (v.w == 1.0f);
  }
  if (!ok) atomicAnd(&ok_s, 0);
  __syncthreads();
  if (t == 0) flags[(b * 32 + kt) * 16 + qt] = ok_s;
}

// ---------------------------------------------------------------------------
// GEMM core: C[8192x1024] = A @ BT^T + bias. 128x128 tile, BK=64, 4 waves.
// ---------------------------------------------------------------------------
__device__ __forceinline__ void gemm_body(const u16* __restrict__ A,
                                          const u16* __restrict__ BT,
                                          const float* __restrict__ bias,
                                          void* __restrict__ outp, int mode,
                                          int nt, int mt, char* sm) {
  const int K = 1024;
  int m0 = mt * 128, n0 = nt * 128;
  int tid = threadIdx.x, w = tid >> 6, l = tid & 63, l15 = l & 15, l4 = l >> 4;
  int wm = w >> 1, wn = w & 1;

  size_t goff_a[4], goff_b[4];
  int lbase[4];
  for (int i = 0; i < 4; i++) {
    int gi = (w * 4 + i) * 64 + l;
    int row = gi >> 3, g = gi & 7;
    int gx = g ^ (row & 7);
    goff_a[i] = (size_t)(m0 + row) * K + gx * 8;
    goff_b[i] = (size_t)(n0 + row) * K + gx * 8;
    lbase[i] = (w * 4 + i) * 1024;
  }

  f32x4 acc[4][4] = {};
  for (int t = 0; t < 16; t++) {
    int k0 = t * 64;
    for (int i = 0; i < 4; i++) {
      GLDS16(A + goff_a[i] + k0, sm + lbase[i]);
      GLDS16(BT + goff_b[i] + k0, sm + 16384 + lbase[i]);
    }
    __syncthreads();
#pragma unroll
    for (int kk = 0; kk < 2; kk++) {
      int kb = kk * 64 + l4 * 16;
      bf16x8 af[4], bf[4];
#pragma unroll
      for (int mi = 0; mi < 4; mi++) {
        int row = wm * 64 + mi * 16 + l15;
        af[mi] = *(const bf16x8*)(sm + row * 128 + (kb ^ ((row & 7) << 4)));
      }
#pragma unroll
      for (int nj = 0; nj < 4; nj++) {
        int row = wn * 64 + nj * 16 + l15;
        bf[nj] = *(const bf16x8*)(sm + 16384 + row * 128 + (kb ^ ((row & 7) << 4)));
      }
#pragma unroll
      for (int mi = 0; mi < 4; mi++)
#pragma unroll
        for (int nj = 0; nj < 4; nj++)
          acc[mi][nj] = __builtin_amdgcn_mfma_f32_16x16x32_bf16(af[mi], bf[nj], acc[mi][nj], 0, 0, 0);
    }
    __syncthreads();
  }

  if (mode == 3) {
    float* out = (float*)outp;
#pragma unroll
    for (int mi = 0; mi < 4; mi++)
#pragma unroll
      for (int nj = 0; nj < 4; nj++)
#pragma unroll
        for (int r = 0; r < 4; r++) {
          int mg = m0 + wm * 64 + mi * 16 + l4 * 4 + r;
          int ng = n0 + wn * 64 + nj * 16 + l15;
          out[(size_t)mg * 1024 + ng] = acc[mi][nj][r] + bias[ng];
        }
  } else if (mode == 2) {
    u16* vt = (u16*)outp;
#pragma unroll
    for (int mi = 0; mi < 4; mi++)
#pragma unroll
      for (int nj = 0; nj < 4; nj++) {
        int ng = n0 + wn * 64 + nj * 16 + l15;
        int h = ng >> 6, d = ng & 63;
        int mgb = m0 + wm * 64 + mi * 16 + l4 * 4;
        int b = mgb >> 11, s = mgb & 2047;
        float bs = bias[ng];
        u16x4 pk;
#pragma unroll
        for (int r = 0; r < 4; r++) pk[r] = f2bf(acc[mi][nj][r] + bs);
        *(u16x4*)(vt + ((size_t)(b * Hn + h) * DHn + d) * Sn + s) = pk;
      }
  } else {
    u16* oh = (u16*)outp;
    float sc = (mode == 0) ? 0.125f : 1.0f;
#pragma unroll
    for (int mi = 0; mi < 4; mi++)
#pragma unroll
      for (int nj = 0; nj < 4; nj++) {
        int ng = n0 + wn * 64 + nj * 16 + l15;
        int h = ng >> 6, d = ng & 63;
        float bs = bias[ng];
#pragma unroll
        for (int r = 0; r < 4; r++) {
          int mg = m0 + wm * 64 + mi * 16 + l4 * 4 + r;
          int b = mg >> 11, s = mg & 2047;
          oh[((size_t)(b * Hn + h) * Sn + s) * DHn + d] = f2bf((acc[mi][nj][r] + bs) * sc);
        }
      }
  }
}

// out-GEMM, 1D grid 512, XCD-chunked swizzle (chunk = 64)
__global__ __launch_bounds__(256) void gemmO_k(const u16* __restrict__ A,
                                               const u16* __restrict__ BT,
                                               const float* __restrict__ bias,
                                               float* __restrict__ outp) {
  __shared__ __align__(16) char sm[32768];
  int hw = blockIdx.x;
  int lg = (hw & 7) * 64 + (hw >> 3);
  int nt = lg & 7, mt = lg >> 3;
  gemm_body(A, BT, bias, (void*)outp, 3, nt, mt, sm);
}

// fused QKV projection, 1D grid 1536, XCD-chunked swizzle (chunk = 192)
__global__ __launch_bounds__(256) void gemm3_k(const u16* __restrict__ Ab,
                                               const u16* __restrict__ BTb,
                                               const float* __restrict__ b0,
                                               const float* __restrict__ b1,
                                               const float* __restrict__ b2,
                                               u16* __restrict__ outb) {
  __shared__ __align__(16) char sm[32768];
  int hw = blockIdx.x;
  int lg = (hw & 7) * 192 + (hw >> 3);
  int z = lg >> 9, r = lg & 511;
  int nt = r & 7, mt = r >> 3;
  const u16* A = Ab + (size_t)z * 8388608;
  const u16* BT = BTb + (size_t)z * 1048576;
  const float* bias = z == 0 ? b0 : z == 1 ? b1 : b2;
  u16* out = outb + (size_t)z * 8388608;
  gemm_body(A, BT, bias, (void*)out, z, nt, mt, sm);
}

// ---------------------------------------------------------------------------
// Attention. 1D grid 1024, XCD-chunked (chunk=128 -> all 16 qt of a (b,h)
// share an XCD L2). 4 waves, QBLK=128, KBLK=64.
// S^T = mfma(K, Q): lane(l15,l4): sq=w*32+ni*16+l15, sk=mi*16+l4*4+r.
// Pass1 (m,l): 1 barrier/tile. Pass2: 1 barrier/tile (P is wave-private LDS).
// LDS: K0 8K | K1 8K | V0 8K | V1 8K | P 16K = 48KB.
// ---------------------------------------------------------------------------
#define K0_OFF 0
#define K1_OFF 8192
#define V0_OFF 16384
#define V1_OFF 24576
#define P_OFF  32768

__global__ __launch_bounds__(256) void attn_k(
    const u16* __restrict__ qh, const u16* __restrict__ kh,
    const u16* __restrict__ vt, const float* __restrict__ mask,
    const int* __restrict__ flags, float* __restrict__ attn,
    u16* __restrict__ ctxc) {
  __shared__ __align__(16) char sm[49152];
  int hw = blockIdx.x;
  int lg = (hw & 7) * 128 + (hw >> 3);
  int qt = lg & 15, h = (lg >> 4) & 15, b = lg >> 8;
  int bh = b * Hn + h;
  int tid = threadIdx.x, w = tid >> 6, l = tid & 63, l15 = l & 15, l4 = l >> 4;

  const u16* Qg = qh + ((size_t)bh * Sn + qt * 128) * DHn;
  const u16* Kg = kh + (size_t)bh * Sn * DHn;
  const u16* Vg = vt + (size_t)bh * DHn * Sn;
  const float* Mg = mask + (size_t)b * Sn * Sn + (size_t)(qt * 128) * Sn;

  // all 32 tile flags -> bitmask (wave-uniform)
  u32 fl = (u32)__ballot(l < 32 && flags[(b * 32 + l) * 16 + qt] != 0);

  int srow[2], sgx8[2], sdst[2];
  for (int i = 0; i < 2; i++) {
    int gid = i * 256 + tid, row = gid >> 3, g = gid & 7;
    srow[i] = row; sgx8[i] = (g ^ (row & 7)) * 8; sdst[i] = gid * 16;
  }
#define STAGE_K(t, buf)                                                        \
  for (int i = 0; i < 2; i++)                                                  \
    GLDS16(Kg + (size_t)((t) * 64 + srow[i]) * DHn + sgx8[i], sm + (buf) + sdst[i]);
#define STAGE_V(t, buf)                                                        \
  for (int i = 0; i < 2; i++)                                                  \
    GLDS16(Vg + (size_t)srow[i] * Sn + (t) * 64 + sgx8[i], sm + (buf) + sdst[i]);

  bf16x8 qf[2][2];
#pragma unroll
  for (int ni = 0; ni < 2; ni++)
#pragma unroll
    for (int kk = 0; kk < 2; kk++)
      qf[ni][kk] = *(const bf16x8*)(Qg + (size_t)(w * 32 + ni * 16 + l15) * DHn + kk * 32 + l4 * 8);

  float m_run[2] = {-1e30f, -1e30f}, l_run[2] = {0.f, 0.f};

  // ---------------- pass 1: running (m, l); 1 barrier/tile ----------------
  STAGE_K(0, K0_OFF);
  for (int t = 0; t < 32; t++) {
    int kcur = (t & 1) ? K1_OFF : K0_OFF;
    __syncthreads();
    if (t < 31) { int knxt = (t & 1) ? K0_OFF : K1_OFF; STAGE_K(t + 1, knxt); }
    f32x4 s[4][2] = {};
#pragma unroll
    for (int kk = 0; kk < 2; kk++) {
      int kb = kk * 64 + l4 * 16;
      bf16x8 a[4];
#pragma unroll
      for (int mi = 0; mi < 4; mi++) {
        int row = mi * 16 + l15;
        a[mi] = *(const bf16x8*)(sm + kcur + row * 128 + (kb ^ ((row & 7) << 4)));
      }
#pragma unroll
      for (int mi = 0; mi < 4; mi++)
#pragma unroll
        for (int ni = 0; ni < 2; ni++)
          s[mi][ni] = __builtin_amdgcn_mfma_f32_16x16x32_bf16(a[mi], qf[ni][kk], s[mi][ni], 0, 0, 0);
    }
    if (!((fl >> t) & 1)) {
#pragma unroll
      for (int ni = 0; ni < 2; ni++) {
        const float* mrow = Mg + (size_t)(w * 32 + ni * 16 + l15) * Sn + t * 64;
#pragma unroll
        for (int mi = 0; mi < 4; mi++) {
          f32x4 mv = *(const f32x4*)(mrow + mi * 16 + l4 * 4);
#pragma unroll
          for (int r = 0; r < 4; r++)
            s[mi][ni][r] = s[mi][ni][r] * mv[r] - 1e6f * (1.f - mv[r]);
        }
      }
    }
#pragma unroll
    for (int ni = 0; ni < 2; ni++) {
      float tmax = -1e30f;
#pragma unroll
      for (int mi = 0; mi < 4; mi++)
#pragma unroll
        for (int r = 0; r < 4; r++) tmax = fmaxf(tmax, s[mi][ni][r]);
      tmax = fmaxf(tmax, __shfl_xor(tmax, 16));
      tmax = fmaxf(tmax, __shfl_xor(tmax, 32));
      float mn = fmaxf(m_run[ni], tmax);
      float sum = 0.f;
#pragma unroll
      for (int mi = 0; mi < 4; mi++)
#pragma unroll
        for (int r = 0; r < 4; r++) sum += __expf(s[mi][ni][r] - mn);
      sum += __shfl_xor(sum, 16);
      sum += __shfl_xor(sum, 32);
      l_run[ni] = l_run[ni] * __expf(m_run[ni] - mn) + sum;
      m_run[ni] = mn;
    }
  }
  float linv[2] = {1.f / l_run[0], 1.f / l_run[1]};

  // ---------------- pass 2: attn store + PV; 1 barrier/tile ----------------
  f32x4 ctx[4][2] = {};
  STAGE_K(0, K0_OFF);
  STAGE_V(0, V0_OFF);
  for (int t = 0; t < 32; t++) {
    int kcur = (t & 1) ? K1_OFF : K0_OFF;
    int vcur = (t & 1) ? V1_OFF : V0_OFF;
    __syncthreads();                         // stages drained + visible
    if (t < 31) {
      int knxt = (t & 1) ? K0_OFF : K1_OFF;
      int vnxt = (t & 1) ? V0_OFF : V1_OFF;
      STAGE_K(t + 1, knxt);
      STAGE_V(t + 1, vnxt);
    }
    f32x4 s[4][2] = {};
#pragma unroll
    for (int kk = 0; kk < 2; kk++) {
      int kb = kk * 64 + l4 * 16;
      bf16x8 a[4];
#pragma unroll
      for (int mi = 0; mi < 4; mi++) {
        int row = mi * 16 + l15;
        a[mi] = *(const bf16x8*)(sm + kcur + row * 128 + (kb ^ ((row & 7) << 4)));
      }
#pragma unroll
      for (int mi = 0; mi < 4; mi++)
#pragma unroll
        for (int ni = 0; ni < 2; ni++)
          s[mi][ni] = __builtin_amdgcn_mfma_f32_16x16x32_bf16(a[mi], qf[ni][kk], s[mi][ni], 0, 0, 0);
    }
    if (!((fl >> t) & 1)) {
#pragma unroll
      for (int ni = 0; ni < 2; ni++) {
        const float* mrow = Mg + (size_t)(w * 32 + ni * 16 + l15) * Sn + t * 64;
#pragma unroll
        for (int mi = 0; mi < 4; mi++) {
          f32x4 mv = *(const f32x4*)(mrow + mi * 16 + l4 * 4);
#pragma unroll
          for (int r = 0; r < 4; r++)
            s[mi][ni][r] = s[mi][ni][r] * mv[r] - 1e6f * (1.f - mv[r]);
        }
      }
    }
#pragma unroll
    for (int ni = 0; ni < 2; ni++)
#pragma unroll
      for (int mi = 0; mi < 4; mi++)
#pragma unroll
        for (int r = 0; r < 4; r++) s[mi][ni][r] = __expf(s[mi][ni][r] - m_run[ni]);
    // attn store first (acks drain under P-pack + PV)
#pragma unroll
    for (int ni = 0; ni < 2; ni++) {
      float* arow = attn + ((size_t)bh * Sn + qt * 128 + w * 32 + ni * 16 + l15) * Sn + t * 64;
#pragma unroll
      for (int mi = 0; mi < 4; mi++) {
        f32x4 o;
#pragma unroll
        for (int r = 0; r < 4; r++) o[r] = s[mi][ni][r] * linv[ni];
        *(f32x4*)(arow + mi * 16 + l4 * 4) = o;
      }
    }
    // P -> LDS (bf16, wave-private rows; no barrier needed before PV)
#pragma unroll
    for (int ni = 0; ni < 2; ni++) {
      int q = w * 32 + ni * 16 + l15;
#pragma unroll
      for (int mi = 0; mi < 4; mi++) {
        u16x4 pk;
#pragma unroll
        for (int r = 0; r < 4; r++) pk[r] = f2bf(s[mi][ni][r]);
        int kb = mi * 32 + l4 * 8;
        *(u16x4*)(sm + P_OFF + q * 128 + (kb ^ ((q & 7) << 4))) = pk;
      }
    }
    // PV: ctx^T += Vt x P^T (bp reads own wave's P rows only)
#pragma unroll
    for (int kk = 0; kk < 2; kk++) {
      int kb = kk * 64 + l4 * 16;
      bf16x8 av[4], bp[2];
#pragma unroll
      for (int mi = 0; mi < 4; mi++) {
        int row = mi * 16 + l15;
        av[mi] = *(const bf16x8*)(sm + vcur + row * 128 + (kb ^ ((row & 7) << 4)));
      }
#pragma unroll
      for (int ni = 0; ni < 2; ni++) {
        int q = w * 32 + ni * 16 + l15;
        bp[ni] = *(const bf16x8*)(sm + P_OFF + q * 128 + (kb ^ ((q & 7) << 4)));
      }
#pragma unroll
      for (int mi = 0; mi < 4; mi++)
#pragma unroll
        for (int ni = 0; ni < 2; ni++)
          ctx[mi][ni] = __builtin_amdgcn_mfma_f32_16x16x32_bf16(av[mi], bp[ni], ctx[mi][ni], 0, 0, 0);
    }
  }

  // ctx epilogue: normalize, wave-private LDS pack, barrier, coalesced store
#pragma unroll
  for (int ni = 0; ni < 2; ni++) {
    int q = w * 32 + ni * 16 + l15;
#pragma unroll
    for (int mi = 0; mi < 4; mi++) {
      u16x4 ck;
#pragma unroll
      for (int r = 0; r < 4; r++) ck[r] = f2bf(ctx[mi][ni][r] * linv[ni]);
      int db = mi * 32 + l4 * 8;
      *(u16x4*)(sm + P_OFF + q * 128 + (db ^ ((q & 7) << 4))) = ck;
    }
  }
  __syncthreads();
  {
    int q = tid >> 1, hf = tid & 1;
    u16* dst = ctxc + ((size_t)b * Sn + qt * 128 + q) * Dn + h * DHn + hf * 32;
#pragma unroll
    for (int c4 = 0; c4 < 4; c4++) {
      int db = hf * 64 + c4 * 16;
      i32x4 v = *(const i32x4*)(sm + P_OFF + q * 128 + (db ^ ((q & 7) << 4)));
      *(i32x4*)(dst + c4 * 8) = v;
    }
  }
}

// ---------------------------------------------------------------------------
extern "C" void kernel_launch(void* const* d_in, const int* in_sizes, int n_in,
                              void* d_out, int out_size, void* d_ws, size_t ws_size,
                              hipStream_t stream) {
  const float* v_f  = (const float*)d_in[0];
  const float* k_f  = (const float*)d_in[1];
  const float* q_f  = (const float*)d_in[2];
  const float* mask = (const float*)d_in[3];
  const float* wq_w = (const float*)d_in[4];
  const float* wq_b = (const float*)d_in[5];
  const float* wk_w = (const float*)d_in[6];
  const float* wk_b = (const float*)d_in[7];
  const float* wv_w = (const float*)d_in[8];
  const float* wv_b = (const float*)d_in[9];
  const float* wo_w = (const float*)d_in[10];
  const float* wo_b = (const float*)d_in[11];

  char* ws = (char*)d_ws;
  u16*   qbf  = (u16*)(ws + 0);             // q,k,v bf16 slabs (contig)
  u16*   wT   = (u16*)(ws + 50331648);      // wqT,wkT,wvT,woT (contig, 2MB ea)
  u16*   woT  = (u16*)(ws + 56623104);
  u16*   qhp  = (u16*)(ws + 58720256);      // Qh, Kh, Vt slabs (contig, 16MB ea)
  u16*   khp  = (u16*)(ws + 75497472);
  u16*   vtp  = (u16*)(ws + 92274688);
  u16*   ctxc = (u16*)(ws + 109051904);
  int*   flg  = (int*)(ws + 125829120);

  float* out  = (float*)d_out;
  float* attn = out + (size_t)Bn * Sn * Dn;

  cast3_k<<<12288, 256, 0, stream>>>(q_f, k_f, v_f, qbf);
  castWT4_k<<<dim3(16, 16, 4), 256, 0, stream>>>(wq_w, wk_w, wv_w, wo_w, wT);
  flags_k<<<dim3(16, 32, 4), 256, 0, stream>>>(mask, flg);

  gemm3_k<<<1536, 256, 0, stream>>>(qbf, wT, wq_b, wk_b, wv_b, qhp);

  attn_k<<<1024, 256, 0, stream>>>(qhp, khp, vtp, mask, flg, attn, ctxc);

  gemmO_k<<<512, 256, 0, stream>>>(ctxc, woT, wo_b, out);
}